// Round 1
// baseline (740.675 us; speedup 1.0000x reference)
//
#include <hip/hip_runtime.h>
#include <hip/hip_bf16.h>

typedef __bf16 bf16x8 __attribute__((ext_vector_type(8)));
typedef float  f32x4  __attribute__((ext_vector_type(4)));

constexpr int D = 128;   // embedding dim
constexpr int P = 256;   // prototypes
constexpr float EPS = 1e-12f;

// Each block: 4 waves. Wave w owns columns [w*64, w*64+64) (4 ntiles of 16).
// B (prototypes) fragments live in registers, loaded once per block.
// Grid-stride loop over 16-row tiles of embeddings; all 4 waves share the
// same 16 rows (plain loads -> waves 1-3 hit L1/MSHR-merge, no HBM overfetch).
// Software-pipelined: next tile's raw A loads are issued right after the
// current tile's conversion, so HBM latency hides under shuffles+MFMA+stores.
__global__ __launch_bounds__(256, 3)
void proto_dist_kernel(const float* __restrict__ emb,
                       const float* __restrict__ proto,
                       float* __restrict__ out,
                       int N, int ntiles)
{
    const int lane = threadIdx.x & 63;
    const int wave = threadIdx.x >> 6;
    const int quad = lane >> 4;
    const int l15  = lane & 15;
    const int colbase = wave * 64;

    // ---- Load B fragments (bf16) + per-column squared norms p2 ----
    // B-operand layout (16x16x32): lane holds B[k = quad*8+j][n = lane&15],
    // i.e. proto[n][k0..k0+7] -> 8 consecutive fp32 -> 2x float4.
    bf16x8 bfrag[4][4];   // [ntile][kstep]
    float  p2[4];
    #pragma unroll
    for (int t = 0; t < 4; ++t) {
        const int n = colbase + t * 16 + l15;
        const float* src = proto + n * D + quad * 8;
        float s = 0.f;
        #pragma unroll
        for (int ks = 0; ks < 4; ++ks) {
            f32x4 lo = *(const f32x4*)(src + ks * 32);
            f32x4 hi = *(const f32x4*)(src + ks * 32 + 4);
            s += lo.x*lo.x + lo.y*lo.y + lo.z*lo.z + lo.w*lo.w;
            s += hi.x*hi.x + hi.y*hi.y + hi.z*hi.z + hi.w*hi.w;
            bf16x8 f;
            f[0]=(__bf16)lo.x; f[1]=(__bf16)lo.y; f[2]=(__bf16)lo.z; f[3]=(__bf16)lo.w;
            f[4]=(__bf16)hi.x; f[5]=(__bf16)hi.y; f[6]=(__bf16)hi.z; f[7]=(__bf16)hi.w;
            bfrag[t][ks] = f;
        }
        // p2 partial covers this lane's 32 k-values; sum the 4 quads.
        s += __shfl_xor(s, 16);
        s += __shfl_xor(s, 32);
        p2[t] = s;   // full ||proto[col]||^2, col = colbase + t*16 + l15
    }

    // ---- Software-pipeline state: raw fp32 A for the *current* tile ----
    f32x4 rlo[4], rhi[4];
    {
        const int row0 = blockIdx.x * 16;
        int rowA = row0 + l15;
        if (rowA > N - 1) rowA = N - 1;
        const float* arow = emb + (long)rowA * D + quad * 8;
        #pragma unroll
        for (int ks = 0; ks < 4; ++ks) {
            rlo[ks] = *(const f32x4*)(arow + ks * 32);
            rhi[ks] = *(const f32x4*)(arow + ks * 32 + 4);
        }
    }

    for (int tile = blockIdx.x; tile < ntiles; tile += gridDim.x) {
        // ---- Convert in-flight raw A -> fragments + partial e2 (fp32) ----
        // (this is where the compiler's vmcnt wait for the loads lands)
        bf16x8 afrag[4];
        float e2p = 0.f;
        #pragma unroll
        for (int ks = 0; ks < 4; ++ks) {
            f32x4 lo = rlo[ks], hi = rhi[ks];
            e2p += lo.x*lo.x + lo.y*lo.y + lo.z*lo.z + lo.w*lo.w;
            e2p += hi.x*hi.x + hi.y*hi.y + hi.z*hi.z + hi.w*hi.w;
            bf16x8 f;
            f[0]=(__bf16)lo.x; f[1]=(__bf16)lo.y; f[2]=(__bf16)lo.z; f[3]=(__bf16)lo.w;
            f[4]=(__bf16)hi.x; f[5]=(__bf16)hi.y; f[6]=(__bf16)hi.z; f[7]=(__bf16)hi.w;
            afrag[ks] = f;
        }

        // ---- Prefetch next tile's raw A (overlaps MFMA + epilogue) ----
        const int tnext = tile + gridDim.x;
        if (tnext < ntiles) {
            const int row0n = tnext * 16;
            int rowA = row0n + l15;
            if (rowA > N - 1) rowA = N - 1;
            const float* arow = emb + (long)rowA * D + quad * 8;
            #pragma unroll
            for (int ks = 0; ks < 4; ++ks) {
                rlo[ks] = *(const f32x4*)(arow + ks * 32);
                rhi[ks] = *(const f32x4*)(arow + ks * 32 + 4);
            }
        }

        // ---- e2 reduce across quads (full ||emb[row0 + l15]||^2) ----
        float e2full = e2p;
        e2full += __shfl_xor(e2full, 16);
        e2full += __shfl_xor(e2full, 32);

        // ---- MFMA cross terms: acc[t] = emb_tile x proto_cols(t) ----
        f32x4 acc[4];
        const f32x4 zero = {0.f, 0.f, 0.f, 0.f};
        #pragma unroll
        for (int t = 0; t < 4; ++t) acc[t] = zero;
        #pragma unroll
        for (int ks = 0; ks < 4; ++ks) {
            #pragma unroll
            for (int t = 0; t < 4; ++t) {
                acc[t] = __builtin_amdgcn_mfma_f32_16x16x32_bf16(
                    afrag[ks], bfrag[t][ks], acc[t], 0, 0, 0);
            }
        }

        // ---- Epilogue: d = -sqrt(max(e2 + p2 - 2*cross, EPS)) ----
        // C/D layout: col = lane&15, row = quad*4 + reg.
        float e2r[4];
        #pragma unroll
        for (int r = 0; r < 4; ++r)
            e2r[r] = __shfl(e2full, quad * 4 + r);

        const int row0 = tile * 16;
        float* obase = out + (long)(row0 + quad * 4) * P + colbase + l15;

        if (row0 + 16 <= N) {
            // fast path: all 16 rows valid (N % 16 == 0 in this problem)
            #pragma unroll
            for (int t = 0; t < 4; ++t) {
                #pragma unroll
                for (int r = 0; r < 4; ++r) {
                    float d2 = fmaf(-2.f, acc[t][r], e2r[r] + p2[t]);
                    d2 = fmaxf(d2, EPS);
                    __builtin_nontemporal_store(-__builtin_sqrtf(d2),
                                                obase + (long)r * P + t * 16);
                }
            }
        } else {
            #pragma unroll
            for (int t = 0; t < 4; ++t) {
                #pragma unroll
                for (int r = 0; r < 4; ++r) {
                    const int grow = row0 + quad * 4 + r;
                    if (grow < N) {
                        float d2 = fmaf(-2.f, acc[t][r], e2r[r] + p2[t]);
                        d2 = fmaxf(d2, EPS);
                        __builtin_nontemporal_store(-__builtin_sqrtf(d2),
                                                    obase + (long)r * P + t * 16);
                    }
                }
            }
        }
    }
}

extern "C" void kernel_launch(void* const* d_in, const int* in_sizes, int n_in,
                              void* d_out, int out_size, void* d_ws, size_t ws_size,
                              hipStream_t stream)
{
    const float* emb   = (const float*)d_in[0];
    const float* proto = (const float*)d_in[1];
    float* out = (float*)d_out;

    const int N = in_sizes[0] / D;          // 500000
    const int ntiles = (N + 15) / 16;       // 31250
    int blocks = ntiles < 2048 ? ntiles : 2048;

    proto_dist_kernel<<<dim3(blocks), dim3(256), 0, stream>>>(emb, proto, out, N, ntiles);
}

// Round 2
// 696.955 us; speedup vs baseline: 1.0627x; 1.0627x over previous
//
#include <hip/hip_runtime.h>
#include <hip/hip_bf16.h>

typedef __bf16 bf16x8 __attribute__((ext_vector_type(8)));
typedef float  f32x4  __attribute__((ext_vector_type(4)));

constexpr int D = 128;   // embedding dim
constexpr int P = 256;   // prototypes
constexpr float EPS = 1e-12f;
// LDS row stride in floats. 260 % 32 == 4, so rows 4 apart (the quad spread in
// the epilogue ds_write) land 16 banks apart -> worst case 2-way aliasing (free).
constexpr int LDS_STRIDE = 260;

// Each block: 4 waves. Wave w owns columns [w*64, w*64+64) (4 ntiles of 16).
// B (prototypes) fragments live in registers, loaded once per block.
// Grid-stride loop over 16-row tiles of embeddings; all 4 waves share the
// same 16 rows (plain loads -> waves 1-3 hit L1/MSHR-merge).
// Software-pipelined A loads; output staged through LDS so global stores are
// 1 KB contiguous dwordx4 per wave-instruction instead of 4B scalars.
__global__ __launch_bounds__(256, 3)
void proto_dist_kernel(const float* __restrict__ emb,
                       const float* __restrict__ proto,
                       float* __restrict__ out,
                       int N, int ntiles)
{
    __shared__ float otile[2][16 * LDS_STRIDE];

    const int lane = threadIdx.x & 63;
    const int wave = threadIdx.x >> 6;
    const int quad = lane >> 4;
    const int l15  = lane & 15;
    const int colbase = wave * 64;

    // ---- Load B fragments (bf16) + per-column squared norms p2 ----
    // B-operand layout (16x16x32): lane holds B[k = quad*8+j][n = lane&15],
    // i.e. proto[n][k0..k0+7] -> 8 consecutive fp32 -> 2x float4.
    bf16x8 bfrag[4][4];   // [ntile][kstep]
    float  p2[4];
    #pragma unroll
    for (int t = 0; t < 4; ++t) {
        const int n = colbase + t * 16 + l15;
        const float* src = proto + n * D + quad * 8;
        float s = 0.f;
        #pragma unroll
        for (int ks = 0; ks < 4; ++ks) {
            f32x4 lo = *(const f32x4*)(src + ks * 32);
            f32x4 hi = *(const f32x4*)(src + ks * 32 + 4);
            s += lo.x*lo.x + lo.y*lo.y + lo.z*lo.z + lo.w*lo.w;
            s += hi.x*hi.x + hi.y*hi.y + hi.z*hi.z + hi.w*hi.w;
            bf16x8 f;
            f[0]=(__bf16)lo.x; f[1]=(__bf16)lo.y; f[2]=(__bf16)lo.z; f[3]=(__bf16)lo.w;
            f[4]=(__bf16)hi.x; f[5]=(__bf16)hi.y; f[6]=(__bf16)hi.z; f[7]=(__bf16)hi.w;
            bfrag[t][ks] = f;
        }
        // p2 partial covers this lane's 32 k-values; sum the 4 quads.
        s += __shfl_xor(s, 16);
        s += __shfl_xor(s, 32);
        p2[t] = s;   // full ||proto[col]||^2, col = colbase + t*16 + l15
    }

    // ---- Software-pipeline state: raw fp32 A for the *current* tile ----
    f32x4 rlo[4], rhi[4];
    {
        const int row0 = blockIdx.x * 16;
        int rowA = row0 + l15;
        if (rowA > N - 1) rowA = N - 1;
        const float* arow = emb + (long)rowA * D + quad * 8;
        #pragma unroll
        for (int ks = 0; ks < 4; ++ks) {
            rlo[ks] = *(const f32x4*)(arow + ks * 32);
            rhi[ks] = *(const f32x4*)(arow + ks * 32 + 4);
        }
    }

    int par = 0;
    for (int tile = blockIdx.x; tile < ntiles; tile += gridDim.x, par ^= 1) {
        // ---- Convert in-flight raw A -> fragments + partial e2 (fp32) ----
        bf16x8 afrag[4];
        float e2p = 0.f;
        #pragma unroll
        for (int ks = 0; ks < 4; ++ks) {
            f32x4 lo = rlo[ks], hi = rhi[ks];
            e2p += lo.x*lo.x + lo.y*lo.y + lo.z*lo.z + lo.w*lo.w;
            e2p += hi.x*hi.x + hi.y*hi.y + hi.z*hi.z + hi.w*hi.w;
            bf16x8 f;
            f[0]=(__bf16)lo.x; f[1]=(__bf16)lo.y; f[2]=(__bf16)lo.z; f[3]=(__bf16)lo.w;
            f[4]=(__bf16)hi.x; f[5]=(__bf16)hi.y; f[6]=(__bf16)hi.z; f[7]=(__bf16)hi.w;
            afrag[ks] = f;
        }

        // ---- Prefetch next tile's raw A (overlaps MFMA + epilogue) ----
        const int tnext = tile + gridDim.x;
        if (tnext < ntiles) {
            int rowA = tnext * 16 + l15;
            if (rowA > N - 1) rowA = N - 1;
            const float* arow = emb + (long)rowA * D + quad * 8;
            #pragma unroll
            for (int ks = 0; ks < 4; ++ks) {
                rlo[ks] = *(const f32x4*)(arow + ks * 32);
                rhi[ks] = *(const f32x4*)(arow + ks * 32 + 4);
            }
        }

        // ---- e2 reduce across quads (full ||emb[row0 + l15]||^2) ----
        float e2full = e2p;
        e2full += __shfl_xor(e2full, 16);
        e2full += __shfl_xor(e2full, 32);

        // ---- MFMA cross terms: acc[t] = emb_tile x proto_cols(t) ----
        f32x4 acc[4];
        const f32x4 zero = {0.f, 0.f, 0.f, 0.f};
        #pragma unroll
        for (int t = 0; t < 4; ++t) acc[t] = zero;
        #pragma unroll
        for (int ks = 0; ks < 4; ++ks) {
            #pragma unroll
            for (int t = 0; t < 4; ++t) {
                acc[t] = __builtin_amdgcn_mfma_f32_16x16x32_bf16(
                    afrag[ks], bfrag[t][ks], acc[t], 0, 0, 0);
            }
        }

        // ---- Epilogue part 1: d = -sqrt(max(e2 + p2 - 2*cross, EPS)) -> LDS ----
        // C/D layout: col = lane&15, row = quad*4 + reg.
        float e2r[4];
        #pragma unroll
        for (int r = 0; r < 4; ++r)
            e2r[r] = __shfl(e2full, quad * 4 + r);

        float* obuf = otile[par];
        #pragma unroll
        for (int t = 0; t < 4; ++t) {
            #pragma unroll
            for (int r = 0; r < 4; ++r) {
                float d2 = fmaf(-2.f, acc[t][r], e2r[r] + p2[t]);
                d2 = fmaxf(d2, EPS);
                obuf[(quad * 4 + r) * LDS_STRIDE + colbase + t * 16 + l15] =
                    -__builtin_amdgcn_sqrtf(d2);
            }
        }

        __syncthreads();

        // ---- Epilogue part 2: coalesced stores. Wave w stores rows w*4..w*4+3,
        // 1 KB contiguous per instruction (64 lanes x dwordx4). ----
        const int row0 = tile * 16;
        const float* rbase = obuf + wave * 4 * LDS_STRIDE + lane * 4;
        #pragma unroll
        for (int rr = 0; rr < 4; ++rr) {
            const int grow = row0 + wave * 4 + rr;
            if (grow < N) {
                f32x4 v = *(const f32x4*)(rbase + rr * LDS_STRIDE);
                __builtin_nontemporal_store(
                    v, (f32x4*)(out + (long)grow * P + lane * 4));
            }
        }
        // No second barrier needed: next iteration writes the OTHER LDS buffer,
        // and the following __syncthreads orders it against these reads.
    }
}

extern "C" void kernel_launch(void* const* d_in, const int* in_sizes, int n_in,
                              void* d_out, int out_size, void* d_ws, size_t ws_size,
                              hipStream_t stream)
{
    const float* emb   = (const float*)d_in[0];
    const float* proto = (const float*)d_in[1];
    float* out = (float*)d_out;

    const int N = in_sizes[0] / D;          // 500000
    const int ntiles = (N + 15) / 16;       // 31250
    int blocks = ntiles < 2048 ? ntiles : 2048;

    proto_dist_kernel<<<dim3(blocks), dim3(256), 0, stream>>>(emb, proto, out, N, ntiles);
}

// Round 3
// 690.901 us; speedup vs baseline: 1.0720x; 1.0088x over previous
//
#include <hip/hip_runtime.h>
#include <hip/hip_bf16.h>

typedef __bf16 bf16x8 __attribute__((ext_vector_type(8)));
typedef float  f32x4  __attribute__((ext_vector_type(4)));

constexpr int D = 128;   // embedding dim
constexpr int P = 256;   // prototypes
constexpr float EPS = 1e-12f;
// Per-wave staging region stride (floats). 66*4 % 32 == 8 -> the 4 quads'
// rows land 8 banks apart on ds_write (2-way aliasing = free, m136);
// row reads at lane stride 1 are 2-way = free.
constexpr int PSTR = 66;

// Each block: 4 waves. Wave w owns columns [w*64, w*64+64) (4 ntiles of 16).
// B (prototypes) fragments live in registers, loaded once per block.
// NO inter-wave barrier: each wave stages its own 16x64 output chunk in a
// wave-private LDS region and stores it as 16 contiguous 256B rows. Waves are
// independent pipelines -> vmcnt stalls in one wave are filled by the others.
// Grid = 768 (3 blocks/CU, all-resident) -> no block turnover, tiny tail.
__global__ __launch_bounds__(256, 3)
void proto_dist_kernel(const float* __restrict__ emb,
                       const float* __restrict__ proto,
                       float* __restrict__ out,
                       int N, int ntiles)
{
    __shared__ float stage[4][16 * PSTR];   // 16.9 KB, wave-private chunks

    const int lane = threadIdx.x & 63;
    const int wave = threadIdx.x >> 6;
    const int quad = lane >> 4;
    const int l15  = lane & 15;
    const int colbase = wave * 64;
    float* const mystage = stage[wave];

    // ---- Load B fragments (bf16) + per-column squared norms p2 ----
    // B-operand layout (16x16x32): lane holds B[k = quad*8+j][n = lane&15],
    // i.e. proto[n][k0..k0+7] -> 8 consecutive fp32 -> 2x float4.
    bf16x8 bfrag[4][4];   // [ntile][kstep]
    float  p2[4];
    #pragma unroll
    for (int t = 0; t < 4; ++t) {
        const int n = colbase + t * 16 + l15;
        const float* src = proto + n * D + quad * 8;
        float s = 0.f;
        #pragma unroll
        for (int ks = 0; ks < 4; ++ks) {
            f32x4 lo = *(const f32x4*)(src + ks * 32);
            f32x4 hi = *(const f32x4*)(src + ks * 32 + 4);
            s += lo.x*lo.x + lo.y*lo.y + lo.z*lo.z + lo.w*lo.w;
            s += hi.x*hi.x + hi.y*hi.y + hi.z*hi.z + hi.w*hi.w;
            bf16x8 f;
            f[0]=(__bf16)lo.x; f[1]=(__bf16)lo.y; f[2]=(__bf16)lo.z; f[3]=(__bf16)lo.w;
            f[4]=(__bf16)hi.x; f[5]=(__bf16)hi.y; f[6]=(__bf16)hi.z; f[7]=(__bf16)hi.w;
            bfrag[t][ks] = f;
        }
        // p2 partial covers this lane's 32 k-values; sum the 4 quads.
        s += __shfl_xor(s, 16);
        s += __shfl_xor(s, 32);
        p2[t] = s;   // full ||proto[col]||^2, col = colbase + t*16 + l15
    }

    // ---- Software-pipeline state: raw fp32 A for the *current* tile ----
    f32x4 rlo[4], rhi[4];
    {
        int rowA = blockIdx.x * 16 + l15;
        if (rowA > N - 1) rowA = N - 1;
        const float* arow = emb + (long)rowA * D + quad * 8;
        #pragma unroll
        for (int ks = 0; ks < 4; ++ks) {
            rlo[ks] = *(const f32x4*)(arow + ks * 32);
            rhi[ks] = *(const f32x4*)(arow + ks * 32 + 4);
        }
    }

    for (int tile = blockIdx.x; tile < ntiles; tile += gridDim.x) {
        // ---- Convert in-flight raw A -> fragments + partial e2 (fp32) ----
        bf16x8 afrag[4];
        float e2p = 0.f;
        #pragma unroll
        for (int ks = 0; ks < 4; ++ks) {
            f32x4 lo = rlo[ks], hi = rhi[ks];
            e2p += lo.x*lo.x + lo.y*lo.y + lo.z*lo.z + lo.w*lo.w;
            e2p += hi.x*hi.x + hi.y*hi.y + hi.z*hi.z + hi.w*hi.w;
            bf16x8 f;
            f[0]=(__bf16)lo.x; f[1]=(__bf16)lo.y; f[2]=(__bf16)lo.z; f[3]=(__bf16)lo.w;
            f[4]=(__bf16)hi.x; f[5]=(__bf16)hi.y; f[6]=(__bf16)hi.z; f[7]=(__bf16)hi.w;
            afrag[ks] = f;
        }

        // ---- Prefetch next tile's raw A (overlaps MFMA + epilogue) ----
        const int tnext = tile + gridDim.x;
        if (tnext < ntiles) {
            int rowA = tnext * 16 + l15;
            if (rowA > N - 1) rowA = N - 1;
            const float* arow = emb + (long)rowA * D + quad * 8;
            #pragma unroll
            for (int ks = 0; ks < 4; ++ks) {
                rlo[ks] = *(const f32x4*)(arow + ks * 32);
                rhi[ks] = *(const f32x4*)(arow + ks * 32 + 4);
            }
        }

        // ---- e2 reduce across quads (full ||emb[row0 + l15]||^2) ----
        float e2full = e2p;
        e2full += __shfl_xor(e2full, 16);
        e2full += __shfl_xor(e2full, 32);

        // ---- MFMA cross terms: acc[t] = emb_tile x proto_cols(t) ----
        f32x4 acc[4];
        const f32x4 zero = {0.f, 0.f, 0.f, 0.f};
        #pragma unroll
        for (int t = 0; t < 4; ++t) acc[t] = zero;
        #pragma unroll
        for (int ks = 0; ks < 4; ++ks) {
            #pragma unroll
            for (int t = 0; t < 4; ++t) {
                acc[t] = __builtin_amdgcn_mfma_f32_16x16x32_bf16(
                    afrag[ks], bfrag[t][ks], acc[t], 0, 0, 0);
            }
        }

        // ---- Epilogue 1: d = -sqrt(max(e2 + p2 - 2*cross, EPS)) -> my LDS ----
        // C/D layout: col = lane&15, row = quad*4 + reg.
        float e2r[4];
        #pragma unroll
        for (int r = 0; r < 4; ++r)
            e2r[r] = __shfl(e2full, quad * 4 + r);

        #pragma unroll
        for (int t = 0; t < 4; ++t) {
            #pragma unroll
            for (int r = 0; r < 4; ++r) {
                float d2 = fmaf(-2.f, acc[t][r], e2r[r] + p2[t]);
                d2 = fmaxf(d2, EPS);
                mystage[(quad * 4 + r) * PSTR + t * 16 + l15] =
                    -__builtin_amdgcn_sqrtf(d2);
            }
        }

        // ---- Epilogue 2: wave-private readback, 256B contiguous nt stores.
        // No barrier: same-wave ds ops are ordered; lgkmcnt covers the RAW.
        const int row0 = tile * 16;
        if (row0 + 16 <= N) {
            #pragma unroll
            for (int row = 0; row < 16; ++row) {
                float v = mystage[row * PSTR + lane];
                __builtin_nontemporal_store(
                    v, out + (long)(row0 + row) * P + colbase + lane);
            }
        } else {
            #pragma unroll
            for (int row = 0; row < 16; ++row) {
                if (row0 + row < N) {
                    float v = mystage[row * PSTR + lane];
                    __builtin_nontemporal_store(
                        v, out + (long)(row0 + row) * P + colbase + lane);
                }
            }
        }
    }
}

extern "C" void kernel_launch(void* const* d_in, const int* in_sizes, int n_in,
                              void* d_out, int out_size, void* d_ws, size_t ws_size,
                              hipStream_t stream)
{
    const float* emb   = (const float*)d_in[0];
    const float* proto = (const float*)d_in[1];
    float* out = (float*)d_out;

    const int N = in_sizes[0] / D;          // 500000
    const int ntiles = (N + 15) / 16;       // 31250
    // 3 blocks/CU x 256 CU: all blocks resident from t=0, no turnover,
    // imbalance ~= 1 tile in ~41.
    int blocks = ntiles < 768 ? ntiles : 768;

    proto_dist_kernel<<<dim3(blocks), dim3(256), 0, stream>>>(emb, proto, out, N, ntiles);
}